// Round 4
// baseline (420.830 us; speedup 1.0000x reference)
//
#include <hip/hip_runtime.h>
#include <hip/hip_bf16.h>

// MultiAttnMatch — cross attention
// B=16, L1=1024, L2=1024, DIN=1024, H=16, DK=DV=64
#define BATCH 16
#define L1D 1024
#define L2D 1024
#define DIN 1024
#define NH 16
#define HD 1024   // NH*DK = NH*DV (output row stride)
#define OHD 3072  // fused QKV row stride

typedef __attribute__((ext_vector_type(4))) float floatx4;
typedef __attribute__((ext_vector_type(8))) short shortx8;
typedef __attribute__((ext_vector_type(8))) unsigned short ushortx8;

#if __has_builtin(__builtin_amdgcn_exp2f)
#define EXP2(x) __builtin_amdgcn_exp2f(x)
#else
#define EXP2(x) exp2f(x)
#endif

static __device__ __forceinline__ unsigned short f2bf(float f) {  // RNE
    union { float f; unsigned u; } v; v.f = f;
    unsigned r = v.u + 0x7fff + ((v.u >> 16) & 1);
    return (unsigned short)(r >> 16);
}
// pack two floats to bf16x2 (round-half-up)
static __device__ __forceinline__ unsigned int pack2bf(float a, float b) {
    union { float f; unsigned u; } x, y; x.f = a; y.f = b;
    return ((y.u + 0x8000u) & 0xffff0000u) | ((x.u + 0x8000u) >> 16);
}

#define GLOBAL_AS __attribute__((address_space(1)))
#define LDS_AS __attribute__((address_space(3)))
static __device__ __forceinline__ void gl2lds16(const unsigned short* g, unsigned short* l) {
    __builtin_amdgcn_global_load_lds((const GLOBAL_AS unsigned int*)g,
                                     (LDS_AS unsigned int*)l, 16, 0, 0);
}

// ---------------------------------------------------------------------------
// prep: cvt x -> xb, cvt y -> yb (fp32->bf16, 8/thread), mask -> float bias
// ---------------------------------------------------------------------------
#define NCVT 8192  // T/2048 blocks per tensor
__global__ void prep_kernel(const float* __restrict__ x, const float* __restrict__ y,
                            unsigned short* __restrict__ xb, unsigned short* __restrict__ yb,
                            const int* __restrict__ ym, float* __restrict__ biasf) {
    int bid = blockIdx.x;
    if (bid < 2 * NCVT) {
        const float* in = bid < NCVT ? x : y;
        unsigned short* o = bid < NCVT ? xb : yb;
        int bb = bid < NCVT ? bid : bid - NCVT;
        size_t i = ((size_t)bb * 256 + threadIdx.x) * 8;
        float4 a = *(const float4*)(in + i);
        float4 b = *(const float4*)(in + i + 4);
        ushortx8 v;
        v[0] = f2bf(a.x); v[1] = f2bf(a.y); v[2] = f2bf(a.z); v[3] = f2bf(a.w);
        v[4] = f2bf(b.x); v[5] = f2bf(b.y); v[6] = f2bf(b.z); v[7] = f2bf(b.w);
        *(ushortx8*)(o + i) = v;
    } else {
        int i = (bid - 2 * NCVT) * 256 + threadIdx.x;
        biasf[i] = ym[i] ? -INFINITY : 0.0f;
    }
}

// ---------------------------------------------------------------------------
// W [DIN][HD] fp32 -> Wt [3*HD][DIN] bf16 (transpose + convert), z = section
// ---------------------------------------------------------------------------
__global__ void wt_kernel(const float* __restrict__ Wq, const float* __restrict__ Wk,
                          const float* __restrict__ Wv, unsigned short* __restrict__ Wt) {
    __shared__ float tile[32][33];
    const float* W = blockIdx.z == 0 ? Wq : (blockIdx.z == 1 ? Wk : Wv);
    unsigned short* dst = Wt + (size_t)blockIdx.z * HD * DIN;
    int bx = blockIdx.x, by = blockIdx.y;
    int tx = threadIdx.x, ty = threadIdx.y;
    for (int i = 0; i < 4; i++)
        tile[ty + i * 8][tx] = W[(size_t)(by * 32 + ty + i * 8) * HD + bx * 32 + tx];
    __syncthreads();
    for (int i = 0; i < 4; i++)
        dst[(size_t)(bx * 32 + ty + i * 8) * DIN + by * 32 + tx] = f2bf(tile[tx][ty + i * 8]);
}

// ---------------------------------------------------------------------------
// Fused QKV GEMM: Out[m][3072] = bf16((A_sec @ W_sec + bias_sec) * scale_sec)
// Tile 128x128, BK=32, global_load_lds + XOR chunk swizzle (conflict-free).
// launch_bounds(256,4): 4 blocks/CU (VGPR 60 + AGPR 64 = 124 <= 128).
// ---------------------------------------------------------------------------
__global__ __launch_bounds__(256, 4) void gemm_kernel(
    const unsigned short* __restrict__ xb, const unsigned short* __restrict__ yb,
    const unsigned short* __restrict__ Wt,
    const float* __restrict__ bq, const float* __restrict__ bk, const float* __restrict__ bvp,
    unsigned short* __restrict__ Out, float qscale)
{
    __shared__ unsigned short As[128 * 32];
    __shared__ unsigned short Bs[128 * 32];
    const int n0 = blockIdx.x * 128;       // 0..3071
    const int m0 = blockIdx.y * 128;
    const int sec = n0 >> 10;
    const unsigned short* A = (sec == 0) ? xb : yb;
    const float* bias = (sec == 0) ? bq : (sec == 1 ? bk : bvp);
    const float scale = (sec == 0) ? qscale : 1.0f;

    const int tid = threadIdx.x;
    const int wid = tid >> 6, lane = tid & 63;
    const int c = lane & 15, qd = lane >> 4;
    const int wm = (wid >> 1) * 64, wn = (wid & 1) * 64;

    int f16a = tid, f16b = 256 + tid;
    int rowA = f16a >> 2, scA = ((f16a & 3) ^ ((rowA >> 1) & 3)) * 8;
    int rowB = f16b >> 2, scB = ((f16b & 3) ^ ((rowB >> 1) & 3)) * 8;
    const int swz = (qd ^ ((c >> 1) & 3)) * 8;

    floatx4 acc[4][4] = {};

    for (int k0 = 0; k0 < DIN; k0 += 32) {
        gl2lds16(A  + (size_t)(m0 + rowA) * DIN + k0 + scA, &As[f16a * 8]);
        gl2lds16(Wt + (size_t)(n0 + rowA) * DIN + k0 + scA, &Bs[f16a * 8]);
        gl2lds16(A  + (size_t)(m0 + rowB) * DIN + k0 + scB, &As[f16b * 8]);
        gl2lds16(Wt + (size_t)(n0 + rowB) * DIN + k0 + scB, &Bs[f16b * 8]);
        __syncthreads();

        shortx8 a[4], b[4];
        for (int mt = 0; mt < 4; mt++)
            a[mt] = *(shortx8*)(&As[(wm + mt * 16 + c) * 32 + swz]);
        for (int nt = 0; nt < 4; nt++)
            b[nt] = *(shortx8*)(&Bs[(wn + nt * 16 + c) * 32 + swz]);
        for (int mt = 0; mt < 4; mt++)
            for (int nt = 0; nt < 4; nt++)
                acc[mt][nt] = __builtin_amdgcn_mfma_f32_16x16x32_bf16(
                    a[mt], b[nt], acc[mt][nt], 0, 0, 0);
        __syncthreads();
    }

    for (int nt = 0; nt < 4; nt++) {
        int gn = n0 + wn + nt * 16 + c;
        float bv = bias[gn & 1023];
        for (int mt = 0; mt < 4; mt++)
            for (int r = 0; r < 4; r++) {
                int gm = m0 + wm + mt * 16 + qd * 4 + r;
                Out[(size_t)gm * OHD + gn] = f2bf((acc[mt][nt][r] + bv) * scale);
            }
    }
}

// ---------------------------------------------------------------------------
// V (Obuf cols 2048..3071, stride 3072) -> Vt [(b*16+h)*64+dv][l2] bf16
// ---------------------------------------------------------------------------
__global__ void vt_kernel(const unsigned short* __restrict__ V,
                          unsigned short* __restrict__ Vt) {
    __shared__ unsigned short t[64][72];
    const int l20 = blockIdx.x * 64;
    const int bh  = blockIdx.y;
    const int b = bh >> 4, h = bh & 15;
    const int tid = threadIdx.x;
    for (int i = 0; i < 2; i++) {
        int idx = i * 256 + tid;
        int row = idx >> 3, col = (idx & 7) * 8;
        *(ushortx8*)(&t[row][col]) =
            *(const ushortx8*)(V + (size_t)(b * L2D + l20 + row) * OHD + h * 64 + col);
    }
    __syncthreads();
    for (int i = 0; i < 2; i++) {
        int idx = i * 256 + tid;
        int dv = idx >> 3, col = (idx & 7) * 8;
        ushortx8 v;
        for (int j = 0; j < 8; j++) v[j] = t[col + j][dv];
        *(ushortx8*)(Vt + (size_t)(bh * 64 + dv) * L2D + l20 + col) = v;
    }
}

// ---------------------------------------------------------------------------
// Attention: computes S^T (swapped MFMA operands) so each lane's P values are
// kv-contiguous for a single q-row -> packed b64 P-stores, scalar psum.
// No-max exp2 softmax; Q-block 128; KV tiles 64; XCD-aware remap.
// ---------------------------------------------------------------------------
__global__ __launch_bounds__(256, 4) void attn_kernel(
    const unsigned short* __restrict__ QK,   // Obuf: Q = col 0, K = col 1024
    const unsigned short* __restrict__ Vt, const float* __restrict__ biasf,
    float* __restrict__ out)
{
    __shared__ unsigned short Ks[64 * 64];
    __shared__ unsigned short Vs[64 * 64];
    __shared__ unsigned short Ps[4][32 * 72];

    int f = blockIdx.y * gridDim.x + blockIdx.x;   // 0..2047
    int bh = (f & 7) * 32 + (f >> 6);
    int q0 = ((f >> 3) & 7) * 128;
    const int b = bh >> 4, h = bh & 15;
    const int tid = threadIdx.x, wid = tid >> 6, lane = tid & 63;
    const int c = lane & 15, qd = lane >> 4;

    // Q A/B fragments (Q pre-scaled by 0.125*log2e in GEMM epilogue)
    shortx8 qf[2][2];
    for (int mt2 = 0; mt2 < 2; mt2++)
        for (int kt = 0; kt < 2; kt++)
            qf[mt2][kt] = *(const shortx8*)(QK +
                (size_t)(b * L1D + q0 + wid * 32 + mt2 * 16 + c) * OHD + h * 64 + kt * 32 + qd * 8);

    floatx4 o[2][4] = {};
    float psum[2] = {0.f, 0.f};

    const unsigned short* Kbase = QK + HD + (size_t)b * L2D * OHD + h * 64;
    const unsigned short* Vbase = Vt + (size_t)bh * 64 * L2D;
    const float* bb = biasf + b * L2D;

    int idxa = tid, idxb = 256 + tid;
    int rowa = idxa >> 3, sca = ((idxa & 7) ^ (rowa & 7)) * 8;
    int rowb = idxb >> 3, scb = ((idxb & 7) ^ (rowb & 7)) * 8;
    const int swz8 = c & 7;

    for (int kv0 = 0; kv0 < L2D; kv0 += 64) {
        gl2lds16(Kbase + (size_t)(kv0 + rowa) * OHD + sca, &Ks[idxa * 8]);
        gl2lds16(Vbase + (size_t)rowa * L2D + kv0 + sca, &Vs[idxa * 8]);
        gl2lds16(Kbase + (size_t)(kv0 + rowb) * OHD + scb, &Ks[idxb * 8]);
        gl2lds16(Vbase + (size_t)rowb * L2D + kv0 + scb, &Vs[idxb * 8]);
        __syncthreads();

        // mask bias for this lane's kv rows: kv = nt*16 + qd*4 + r
        float4 bvv[4];
        for (int nt = 0; nt < 4; nt++)
            bvv[nt] = *(const float4*)(bb + kv0 + nt * 16 + qd * 4);

        for (int mt2 = 0; mt2 < 2; mt2++) {
            // S^T: D[m=kv][n=q] — A = K-frag, B = Q-frag (operands swapped)
            floatx4 z[4];
            for (int nt = 0; nt < 4; nt++) {
                floatx4 zz = {};
                for (int kt = 0; kt < 2; kt++) {
                    shortx8 kf = *(shortx8*)(&Ks[(nt * 16 + c) * 64 + ((kt * 4 + qd) ^ swz8) * 8]);
                    zz = __builtin_amdgcn_mfma_f32_16x16x32_bf16(kf, qf[mt2][kt], zz, 0, 0, 0);
                }
                z[nt] = zz;
            }
            // p = exp2(s + bias); all 16 values belong to q-row c
            float ps = 0.f;
            for (int nt = 0; nt < 4; nt++) {
                float p0 = EXP2(z[nt][0] + bvv[nt].x);
                float p1 = EXP2(z[nt][1] + bvv[nt].y);
                float p2 = EXP2(z[nt][2] + bvv[nt].z);
                float p3 = EXP2(z[nt][3] + bvv[nt].w);
                ps += (p0 + p1) + (p2 + p3);
                uint2 w = { pack2bf(p0, p1), pack2bf(p2, p3) };
                *(uint2*)(&Ps[wid][(mt2 * 16 + c) * 72 + nt * 16 + qd * 4]) = w;
            }
            psum[mt2] += ps;
        }
        // O += P @ V  (P A-frags; same addresses as before)
        for (int mt2 = 0; mt2 < 2; mt2++) {
            shortx8 pf[2];
            for (int kt = 0; kt < 2; kt++)
                pf[kt] = *(shortx8*)(&Ps[wid][(mt2 * 16 + c) * 72 + kt * 32 + qd * 8]);
            for (int nt = 0; nt < 4; nt++)
                for (int kt = 0; kt < 2; kt++) {
                    shortx8 vf = *(shortx8*)(&Vs[(nt * 16 + c) * 64 + ((kt * 4 + qd) ^ swz8) * 8]);
                    o[mt2][nt] = __builtin_amdgcn_mfma_f32_16x16x32_bf16(pf[kt], vf, o[mt2][nt], 0, 0, 0);
                }
        }
        __syncthreads();
    }

    // l[q=c] = sum over the 4 quads; epilogue needs l[q=qd*4+r] via shfl
    for (int mt2 = 0; mt2 < 2; mt2++) {
        float l = psum[mt2];
        l += __shfl_xor(l, 16, 64);
        l += __shfl_xor(l, 32, 64);
        for (int r = 0; r < 4; r++) {
            float inv = 1.0f / __shfl(l, qd * 4 + r, 64);
            size_t rowbase = ((size_t)b * L1D + q0 + wid * 32 + mt2 * 16 + qd * 4 + r) * HD + h * 64;
            for (int nt = 0; nt < 4; nt++)
                out[rowbase + nt * 16 + c] = o[mt2][nt][r] * inv;
        }
    }
}

// ---------------------------------------------------------------------------
extern "C" void kernel_launch(void* const* d_in, const int* in_sizes, int n_in,
                              void* d_out, int out_size, void* d_ws, size_t ws_size,
                              hipStream_t stream) {
    const float* x  = (const float*)d_in[0];
    const float* y  = (const float*)d_in[1];
    const int*  ym  = (const int*)d_in[2];
    const float* Wq = (const float*)d_in[3];
    const float* bq = (const float*)d_in[4];
    const float* Wk = (const float*)d_in[5];
    const float* bk = (const float*)d_in[6];
    const float* Wv = (const float*)d_in[7];
    const float* bv = (const float*)d_in[8];
    float* outp = (float*)d_out;

    const size_t M = (size_t)BATCH * L1D;      // 16384
    const size_t T = M * HD;                   // 16.78M
    unsigned short* Obuf = (unsigned short*)d_ws;     // M*3072 (QKV fused)
    unsigned short* xb   = Obuf + M * OHD;            // T ; reused as Vt after gemm
    unsigned short* yb   = xb + T;                    // T
    unsigned short* Wt   = yb + T;                    // 3072*1024
    float* biasf         = (float*)(Wt + (size_t)OHD * DIN);
    // total ~174 MB

    const float QSCALE = 0.125f * 1.44269504088896340736f;  // 1/sqrt(64)*log2(e)

    prep_kernel<<<2 * NCVT + (BATCH * L2D) / 256, 256, 0, stream>>>(x, y, xb, yb, ym, biasf);
    wt_kernel<<<dim3(HD / 32, DIN / 32, 3), dim3(32, 8), 0, stream>>>(Wq, Wk, Wv, Wt);
    gemm_kernel<<<dim3(OHD / 128, M / 128), 256, 0, stream>>>(xb, yb, Wt, bq, bk, bv, Obuf, QSCALE);
    vt_kernel<<<dim3(L2D / 64, BATCH * NH), 256, 0, stream>>>(Obuf + 2 * HD, xb);
    attn_kernel<<<dim3(L1D / 128, BATCH * NH), 256, 0, stream>>>(Obuf, xb, biasf, outp);
}